// Round 1
// baseline (85.268 us; speedup 1.0000x reference)
//
#include <hip/hip_runtime.h>
#include <hip/hip_bf16.h>

// SlidingGaussianWindow1d: B=16, T=256, C=64, NWIN=224, wsize=32.
// out[b,w,c,d] = corrcoef over t of (W[w,t]*x[b,t,c]), clipped to [-1,1].
//
// Structure:
//  prep_kernel (1 block): builds normalized smoothed-box window Anorm[256]
//    (= conv(gw, box)/max, cropped), finds its support [lo,hi], writes
//    Anorm + (u0, K) to ws.  K = support rounded up to multiple of 16.
//  corr_kernel (3584 blocks, 256 thr): per (b,w), stages yT[c][k] in bf16
//    LDS over the K-sample support (rolled coordinate), computes raw Gram
//    via mfma_f32_32x32x16_bf16 (4 waves = 4 32x32 tiles), corrects for the
//    mean (cov = (G - T*mu*mu)/(T-1)), normalizes by rsqrt(diag), clips,
//    writes 64x64 fp32 tile.

static constexpr int TT   = 256;   // time samples
static constexpr int CC   = 64;    // channels
static constexpr int NW   = 224;   // windows
static constexpr int MAXK = 128;   // max staged support length (actual ~64)
static constexpr int KPAD = MAXK + 8;  // row stride: 136 bf16 = 272 B = 17*16B

typedef short bf16x8 __attribute__((ext_vector_type(8)));
typedef float f32x16 __attribute__((ext_vector_type(16)));

__global__ __launch_bounds__(256) void prep_kernel(const float* __restrict__ alpha,
                                                   float* __restrict__ ws) {
    __shared__ float gw[TT];
    __shared__ float Afull[2 * TT - 1];
    __shared__ float red[256];
    __shared__ int slo, shi;
    const int tid = threadIdx.x;

    float a = alpha[0];
    float scale = 1.0f / (2.0f * a * a);
    float d = (float)(tid - 128);
    gw[tid] = expf(-d * d) * scale;
    if (tid == 0) { slo = TT; shi = -1; }
    __syncthreads();

    // full convolution with box b[112..143]=1; A[n] = sum_j gw[n-j]
    float mx = 0.f;
    for (int n = tid; n < 2 * TT - 1; n += 256) {
        float s = 0.f;
        for (int j = 112; j <= 143; ++j) {
            int g = n - j;
            if (g >= 0 && g < TT) s += gw[g];
        }
        Afull[n] = s;
        mx = fmaxf(mx, s);
    }
    red[tid] = mx;
    __syncthreads();
    for (int off = 128; off > 0; off >>= 1) {
        if (tid < off) red[tid] = fmaxf(red[tid], red[tid + off]);
        __syncthreads();
    }
    float inv = 1.0f / red[0];

    // cropped + normalized window: Anorm[t] = Afull[128+t]/max, t in [0,256)
    float an = Afull[128 + tid] * inv;
    ws[tid] = an;
    if (an > 0.0f) {
        atomicMin(&slo, tid);
        atomicMax(&shi, tid);
    }
    __syncthreads();
    if (tid == 0) {
        int lo = slo, hi = shi;
        if (hi < 0) { lo = 0; hi = 0; }          // paranoia
        int len = hi - lo + 1;
        int K = (len + 15) & ~15;
        if (K > MAXK) K = MAXK;                  // cannot happen for fp32 exp
        int u0 = lo;
        if (u0 + K > TT) u0 = TT - K;
        if (u0 < 0) u0 = 0;
        int* iws = (int*)ws;
        iws[TT]     = u0;
        iws[TT + 1] = K;
    }
}

__global__ __launch_bounds__(256) void corr_kernel(const float* __restrict__ x,
                                                   const float* __restrict__ ws,
                                                   float* __restrict__ out) {
    __shared__ __align__(16) __hip_bfloat16 Yt[CC][KPAD];  // transposed bf16 tile
    __shared__ float wsh[MAXK];
    __shared__ float red[4][CC];
    __shared__ float colsum[CC];
    __shared__ float rdiag[CC];

    const int blk = blockIdx.x;
    const int b = blk / NW;
    const int w = blk - b * NW;
    const int tid = threadIdx.x;

    const int* iws = (const int*)ws;
    const int u0 = iws[TT];
    const int K  = iws[TT + 1];          // multiple of 16, <= MAXK
    // cumulative roll S[w] = sum_{k<=w} (k-111) = (w+1)(w-222)/2 (always even product)
    const int S = ((w + 1) * (w - 222)) / 2;

    if (tid < K) wsh[tid] = ws[u0 + tid];
    __syncthreads();

    const float* xb = x + (size_t)b * TT * CC;
    const int c = tid & 63;
    const int q = tid >> 6;
    float csum = 0.f;
    // stage y^T: Yt[c][uu] = bf16( Anorm[u0+uu] * x[b][(u0+uu-S)&255][c] )
    const int iters = K >> 3;            // 8 u's per iteration (4 waves x 2)
    for (int it = 0; it < iters; ++it) {
        int uu = it * 8 + q * 2;
        int t0 = (u0 + uu - S) & 255;        // two's complement & works for neg
        int t1 = (u0 + uu + 1 - S) & 255;
        float v0 = xb[t0 * CC + c] * wsh[uu];
        float v1 = xb[t1 * CC + c] * wsh[uu + 1];
        __hip_bfloat16 h0 = __float2bfloat16(v0);
        __hip_bfloat16 h1 = __float2bfloat16(v1);
        // column sums from the *quantized* values -> centering is exact for
        // the quantized series (diag of corr == 1 up to fp32 rounding)
        csum += __bfloat162float(h0) + __bfloat162float(h1);
        unsigned short us0 = *(unsigned short*)&h0;
        unsigned short us1 = *(unsigned short*)&h1;
        unsigned pk = ((unsigned)us1 << 16) | (unsigned)us0;
        *(unsigned*)&Yt[c][uu] = pk;         // uu even -> 4B aligned
    }
    red[q][c] = csum;
    __syncthreads();
    if (tid < CC) colsum[tid] = red[0][tid] + red[1][tid] + red[2][tid] + red[3][tid];
    __syncthreads();

    // Gram via MFMA: G = Y^T Y, 4 waves -> 2x2 grid of 32x32 tiles
    const int wv = tid >> 6;
    const int lane = tid & 63;
    const int ti = wv >> 1, tj = wv & 1;
    const int r32 = lane & 31, half = lane >> 5;
    f32x16 acc;
#pragma unroll
    for (int i = 0; i < 16; ++i) acc[i] = 0.f;
    const __hip_bfloat16* arow = &Yt[32 * ti + r32][half * 8];
    const __hip_bfloat16* brow = &Yt[32 * tj + r32][half * 8];
    for (int k0 = 0; k0 < K; k0 += 16) {
        bf16x8 af = *(const bf16x8*)(arow + k0);
        bf16x8 bf = *(const bf16x8*)(brow + k0);
        acc = __builtin_amdgcn_mfma_f32_32x32x16_bf16(af, bf, acc, 0, 0, 0);
    }

    // diagonal -> rsqrt(var); C/D layout: col = lane&31,
    // row = (reg&3) + 8*(reg>>2) + 4*(lane>>5)   [m74/m101 verified]
    constexpr float invT  = 1.0f / 256.0f;
    constexpr float invT1 = 1.0f / 255.0f;
    if (ti == tj) {
        int needHalf = (r32 >> 2) & 1;
        if (half == needHalf) {
            int reg = ((r32 >> 3) << 2) | (r32 & 3);
            float g = acc[0];
#pragma unroll
            for (int rr = 1; rr < 16; ++rr)
                if (rr == reg) g = acc[rr];
            int cg = 32 * ti + r32;
            float mu = colsum[cg] * invT;
            float cv = (g - 256.0f * mu * mu) * invT1;
            rdiag[cg] = rsqrtf(fmaxf(cv, 1e-38f));
        }
    }
    __syncthreads();

    float* outb = out + (size_t)blk * (CC * CC);
#pragma unroll
    for (int rr = 0; rr < 16; ++rr) {
        int row = 32 * ti + (rr & 3) + 8 * (rr >> 2) + 4 * half;
        int col = 32 * tj + r32;
        float mur = colsum[row] * invT;
        float muc = colsum[col] * invT;
        float cv = (acc[rr] - 256.0f * mur * muc) * invT1;
        float cr = cv * rdiag[row] * rdiag[col];
        cr = fminf(1.0f, fmaxf(-1.0f, cr));
        outb[row * CC + col] = cr;
    }
}

extern "C" void kernel_launch(void* const* d_in, const int* in_sizes, int n_in,
                              void* d_out, int out_size, void* d_ws, size_t ws_size,
                              hipStream_t stream) {
    const float* x     = (const float*)d_in[0];
    const float* alpha = (const float*)d_in[1];
    float* out = (float*)d_out;
    float* ws  = (float*)d_ws;

    prep_kernel<<<1, 256, 0, stream>>>(alpha, ws);
    corr_kernel<<<16 * NW, 256, 0, stream>>>(x, ws, out);
}

// Round 2
// 78.139 us; speedup vs baseline: 1.0912x; 1.0912x over previous
//
#include <hip/hip_runtime.h>
#include <hip/hip_bf16.h>

// SlidingGaussianWindow1d: B=16, T=256, C=64, NWIN=224, wsize=32.
// out[b,w,c,d] = corrcoef over t of (W[w,t]*x[b,t,c]), clipped to [-1,1].
//
// Single fused kernel, one (b,w) pair per block (3584 blocks, 256 thr):
//  - window weights computed per-block (cheap): the normalized smoothed-box
//    A[t]/A.max has fixed fp32 support t in [102,153]; we stage K=64 samples
//    at rolled coords [96,160) — zero-weight samples contribute exactly 0,
//    and mean/cov corrections use the full T=256 denominators, so this is
//    exact (not an approximation).
//  - y^T staged in bf16 LDS; raw Gram via mfma_f32_32x32x16_bf16 (4 waves =
//    2x2 grid of 32x32 tiles); mean correction from the *quantized* column
//    sums (diag of corr == 1 up to fp32 rounding); rsqrt-normalize, clip,
//    write 64x64 fp32 tile.

static constexpr int TT   = 256;   // time samples
static constexpr int CC   = 64;    // channels
static constexpr int NW   = 224;   // windows
static constexpr int KS   = 64;    // staged support length (multiple of 16)
static constexpr int U0   = 96;    // support window start (rolled coord)
static constexpr int KPAD = KS + 8; // LDS row stride: 72 bf16 = 144 B (16B-mult)

typedef short bf16x8 __attribute__((ext_vector_type(8)));
typedef float f32x16 __attribute__((ext_vector_type(16)));

__global__ __launch_bounds__(256) void corr_kernel(const float* __restrict__ x,
                                                   const float* __restrict__ alpha,
                                                   float* __restrict__ out) {
    __shared__ float Ed[32];                               // exp(-d^2)*scale, d=-12..12
    __shared__ float Wn[KS];                               // normalized window taps
    __shared__ __align__(16) __hip_bfloat16 Yt[CC][KPAD];  // transposed bf16 tile
    __shared__ float red[4][CC];
    __shared__ float colsum[CC];
    __shared__ float rdiag[CC];

    const int tid = threadIdx.x;
    const int blk = blockIdx.x;
    const int b = blk / NW;
    const int w = blk - b * NW;
    // cumulative roll S[w] = sum_{k<=w} (k-111) = (w+1)(w-222)/2
    const int S = ((w + 1) * (w - 222)) / 2;

    // --- window weights (alpha scale cancels in the ratio; kept for
    //     faithfulness so alpha=0/inf still NaNs like the reference) ---
    if (tid < 25) {
        float a = alpha[0];
        float scale = 1.0f / (2.0f * a * a);
        float d = (float)(tid - 12);
        Ed[tid] = expf(-d * d) * scale;
    }
    __syncthreads();
    if (tid < KS) {
        // A[t] = sum_{j=112..143} E(t-j); A_max = sum_{|d|<=12} E(d)
        float tot = 0.f;
        for (int k = 0; k < 25; ++k) tot += Ed[k];
        int t = U0 + tid;
        int dlo = t - 143, dhi = t - 112;
        if (dlo < -12) dlo = -12;
        if (dhi > 12) dhi = 12;
        float s = 0.f;
        for (int d = dlo; d <= dhi; ++d) s += Ed[d + 12];
        Wn[tid] = s / tot;
    }
    __syncthreads();

    // --- stage y^T: Yt[c][u] = bf16( Wn[u] * x[b][(U0+u-S)&255][c] ) ---
    const float* xb = x + (size_t)b * TT * CC;
    const int c = tid & 63;
    const int q = tid >> 6;
    float csum = 0.f;
#pragma unroll
    for (int it = 0; it < (KS >> 3); ++it) {
        int uu = it * 8 + q * 2;
        int t0 = (U0 + uu - S) & 255;
        int t1 = (U0 + uu + 1 - S) & 255;
        float v0 = xb[t0 * CC + c] * Wn[uu];
        float v1 = xb[t1 * CC + c] * Wn[uu + 1];
        __hip_bfloat16 h0 = __float2bfloat16(v0);
        __hip_bfloat16 h1 = __float2bfloat16(v1);
        // column sums from the quantized values -> exact centering of the
        // quantized series (corr diag == 1 up to fp32 rounding)
        csum += __bfloat162float(h0) + __bfloat162float(h1);
        unsigned short us0 = *(unsigned short*)&h0;
        unsigned short us1 = *(unsigned short*)&h1;
        unsigned pk = ((unsigned)us1 << 16) | (unsigned)us0;
        *(unsigned*)&Yt[c][uu] = pk;             // uu even -> 4B aligned
    }
    red[q][c] = csum;
    __syncthreads();
    if (tid < CC) colsum[tid] = red[0][tid] + red[1][tid] + red[2][tid] + red[3][tid];

    // --- Gram via MFMA: G = Y^T Y, 4 waves -> 2x2 grid of 32x32 tiles ---
    const int wv = tid >> 6;
    const int lane = tid & 63;
    const int ti = wv >> 1, tj = wv & 1;
    const int r32 = lane & 31, half = lane >> 5;
    f32x16 acc;
#pragma unroll
    for (int i = 0; i < 16; ++i) acc[i] = 0.f;
    const __hip_bfloat16* arow = &Yt[32 * ti + r32][half * 8];
    const __hip_bfloat16* brow = &Yt[32 * tj + r32][half * 8];
#pragma unroll
    for (int k0 = 0; k0 < KS; k0 += 16) {
        bf16x8 af = *(const bf16x8*)(arow + k0);
        bf16x8 bf = *(const bf16x8*)(brow + k0);
        acc = __builtin_amdgcn_mfma_f32_32x32x16_bf16(af, bf, acc, 0, 0, 0);
    }
    __syncthreads();   // colsum visible to all waves; accs done

    // --- diagonal -> rsqrt(var); C/D layout: col = lane&31,
    //     row = (reg&3) + 8*(reg>>2) + 4*(lane>>5)   [m74/m101 verified] ---
    constexpr float invT  = 1.0f / 256.0f;
    constexpr float invT1 = 1.0f / 255.0f;
    if (ti == tj) {
        int needHalf = (r32 >> 2) & 1;
        if (half == needHalf) {
            int reg = ((r32 >> 3) << 2) | (r32 & 3);
            float g = acc[0];
#pragma unroll
            for (int rr = 1; rr < 16; ++rr)
                if (rr == reg) g = acc[rr];
            int cg = 32 * ti + r32;
            float mu = colsum[cg] * invT;
            float cv = (g - 256.0f * mu * mu) * invT1;
            rdiag[cg] = rsqrtf(fmaxf(cv, 1e-38f));
        }
    }
    __syncthreads();

    // --- normalize, clip, store ---
    float* outb = out + (size_t)blk * (CC * CC);
#pragma unroll
    for (int rr = 0; rr < 16; ++rr) {
        int row = 32 * ti + (rr & 3) + 8 * (rr >> 2) + 4 * half;
        int col = 32 * tj + r32;
        float mur = colsum[row] * invT;
        float muc = colsum[col] * invT;
        float cv = (acc[rr] - 256.0f * mur * muc) * invT1;
        float cr = cv * rdiag[row] * rdiag[col];
        cr = fminf(1.0f, fmaxf(-1.0f, cr));
        outb[row * CC + col] = cr;
    }
}

extern "C" void kernel_launch(void* const* d_in, const int* in_sizes, int n_in,
                              void* d_out, int out_size, void* d_ws, size_t ws_size,
                              hipStream_t stream) {
    const float* x     = (const float*)d_in[0];
    const float* alpha = (const float*)d_in[1];
    float* out = (float*)d_out;
    (void)d_ws; (void)ws_size;

    corr_kernel<<<16 * NW, 256, 0, stream>>>(x, alpha, out);
}